// Round 13
// baseline (2361.981 us; speedup 1.0000x reference)
//
#include <hip/hip_runtime.h>

// Problem constants (B=16, N=M=1024, D=32)
constexpr float EPSf     = 1e-3f;
constexpr int   MAX_ITER = 100;

// exp2-domain scale: arg = (v - C) * (1/eps) * log2(e)
#define K2      1442.6950408889634f
#define TWOK2   2885.3900817779268f
#define LN2f    0.6931471805599453f
#define INV_LN2 1.4426950408889634f
#define INV_EPS 1000.0f
#define LOGK    (-6.9314616f)   // log(1/1024 + 1e-8)

#define EXP2F(x) __builtin_amdgcn_exp2f(x)   // 2^x
#define LOG2F(x) __builtin_amdgcn_logf(x)    // log2(x)

typedef _Float16 f16x8 __attribute__((ext_vector_type(8)));
typedef float    f32x4 __attribute__((ext_vector_type(4)));

// (m,s) streaming-LSE merge: (ma,sa) <- (ma,sa) (+) (mb,sb)
__device__ __forceinline__ void msmerge(float& ma, float& sa, float mb, float sb)
{
    const float m2 = fmaxf(ma, mb);
    sa = fmaf(sa, EXP2F(ma - m2), sb * EXP2F(mb - m2));
    ma = m2;
}

// ---------------------------------------------------------------------------
// prep: X,Y fp32 -> fp16 copies + fp32 row sum-of-squares (unchanged).
// ---------------------------------------------------------------------------
__global__ __launch_bounds__(256) void prep(
    const float* __restrict__ X, const float* __restrict__ Y,
    _Float16* __restrict__ Xh, _Float16* __restrict__ Yh,
    float* __restrict__ xsq, float* __restrict__ ysq)
{
    const int gid = blockIdx.x * 256 + threadIdx.x;   // 0..32767
    const float* src; _Float16* dst; float* sq; int row;
    if (gid < 16384) { src = X; dst = Xh; sq = xsq; row = gid; }
    else             { src = Y; dst = Yh; sq = ysq; row = gid - 16384; }

    const float4* s4 = (const float4*)(src + (size_t)row * 32);
    float acc = 0.f;
#pragma unroll
    for (int i = 0; i < 4; ++i) {
        float4 a = s4[2 * i], b = s4[2 * i + 1];
        acc += a.x*a.x + a.y*a.y + a.z*a.z + a.w*a.w;
        acc += b.x*b.x + b.y*b.y + b.z*b.z + b.w*b.w;
        f16x8 h = {(_Float16)a.x, (_Float16)a.y, (_Float16)a.z, (_Float16)a.w,
                   (_Float16)b.x, (_Float16)b.y, (_Float16)b.z, (_Float16)b.w};
        *(f16x8*)(dst + (size_t)row * 32 + i * 8) = h;
    }
    sq[row] = acc;
}

// XOR-swizzled LDS slot (r7-proven): conflict-free b128 reads/writes.
#define YSLOT(c, k) (((c) << 5) + (((k) ^ (((c) >> 1) & 3)) << 3))   // f16 units

// ---------------------------------------------------------------------------
// ONE kernel per Sinkhorn iteration. 512 blocks x 1024 threads, 32 rows/block
// (16 waves = 2 row-stripes x 8 col-chunks, 8 MFMA tiles/wave -> e_[32]/lane:
// VGPR ~90, no spill — r12's e_[64] vs the 128-cap spilled to scratch).
//  P0: v_it[j] = msmerge-combine of 32 (m,s) col-partials (1 col/thread).
//  P1: u-update, fast prev-u shift + block-uniform online fallback,
//      RETAINING the 32 exp2 values e_ij per lane.
//  P2 cheap: cs_j = sum_i e_ij * g_i, g_i = 2^{(u_new-u_old)*K2} — no second
//      MFMA/exp2 sweep. g-guard du*K2>30 (r12 allowed 2^100: e values that
//      underflowed to 0 in P1 lost mass ~2^-26 -> absmax 0.125; with g<=2^30
//      lost mass <2^-96 — negligible).
//  P2 exact (absolute-domain online, r10-proven): when P1 fell back, any
//      du*K2>30, or every 8th iter. All gates block-uniform.
// ---------------------------------------------------------------------------
__global__ __launch_bounds__(1024, 1) void sink_iter(
    const _Float16* __restrict__ Xh, const _Float16* __restrict__ Yh,
    const float* __restrict__ xsq, const float* __restrict__ ysq,
    float* __restrict__ u,          // [16][1024]
    float2* __restrict__ Sp,        // [16*32][1024] (m,s) col-partials
    float* __restrict__ err,        // [100][16]
    int it)
{
    __shared__ _Float16 Yl[32768];     // 64 KB B-tile, swizzled; colp aliases
    __shared__ float wk[1024];         // (v_it - ysq) * K2
    __shared__ float bk2[1024];        // ysq * K2 + Mc_j
    __shared__ float mcl[1024];        // Mc_j = (LOGK - v_it/eps)/ln2
    __shared__ float mrg[32][16];      // fast: [:8]; fallback: m [:8], s [8:]
    __shared__ float unew[32];
    __shared__ int s_fb, s_frz, s_big;
    float2* colp = (float2*)Yl;        // [2][1024] after Yl fully consumed

    const int tid = threadIdx.x;
    const int b   = blockIdx.x & 15, blk = blockIdx.x >> 4;   // blk < 32

    if (it > 0) {       // freeze check (reference semantics; err complete)
        if (tid == 0) {
            float e = 0.f;
            const float* ep = err + (it - 1) * 16;
#pragma unroll
            for (int q = 0; q < 16; ++q) e += ep[q];
            s_frz = (e < 1.6f) ? 1 : 0;
        }
        __syncthreads();
        if (s_frz) return;
    }
    if (tid == 0) { s_fb = 0; s_big = 0; }

    {   // stage Yh[b] swizzled + P0 combine v (1 col/thread) + wk/bk2/mcl
        const float4* src = (const float4*)(Yh + ((size_t)b << 15));
#pragma unroll
        for (int i = 0; i < 4; ++i) {
            const int g = tid + (i << 10);
            const int row = g >> 2, k = g & 3;
            *(float4*)(Yl + YSLOT(row, k)) = src[g];
        }
        float vj = 0.f;
        if (it > 0) {
            const float2* sp = Sp + ((size_t)b << 15) + tid;
            float2 p0 = sp[0];
            float M = p0.x, S = p0.y;
#pragma unroll 8
            for (int k = 1; k < 32; ++k) {
                float2 p = sp[k << 10];
                msmerge(M, S, p.x, p.y);
            }
            S = fmaxf(S, 1e-37f);   // anti -inf belt (refresh re-corrects)
            vj = EPSf * (LOGK - (M + LOG2F(S)) * LN2f);
        }
        const float bq = ysq[(b << 10) + tid];
        const float mc = (LOGK - vj * INV_EPS) * INV_LN2;
        wk[tid]  = (vj - bq) * K2;
        bk2[tid] = bq * K2 + mc;
        mcl[tid] = mc;
    }
    __syncthreads();

    const int wave = tid >> 6, lane = tid & 63;
    const int wr = wave >> 3, wc = wave & 7;      // 2 stripes x 8 col-chunks
    const int l15 = lane & 15, l4 = lane >> 4;
    const int rowb = (blk << 5) + (wr << 4);      // wave's 16-row stripe

    const f16x8 afrag = *(const f16x8*)(Xh + ((size_t)b << 15) +
                                        ((size_t)(rowb + l15) << 5) + (l4 << 3));
    const float4 xs4 = *(const float4*)(xsq + (b << 10) + rowb + (l4 << 2));
    const float4 uo4 = *(const float4*)(u + (b << 10) + rowb + (l4 << 2));
    const float xk[4]  = {xs4.x * K2, xs4.y * K2, xs4.z * K2, xs4.w * K2};
    const float u4o[4] = {uo4.x, uo4.y, uo4.z, uo4.w};
    float xm[4];
#pragma unroll
    for (int r = 0; r < 4; ++r)
        xm[r] = xk[r] + (LOGK - u4o[r] * INV_EPS) * INV_LN2;

    // -------- P1 FAST: sums shifted by prev-u, RETAIN e values --------
    float e_[32];
    float s[4] = {0.f, 0.f, 0.f, 0.f};
#pragma unroll
    for (int t = 0; t < 8; ++t) {
        const int col = (wc << 7) + (t << 4) + l15;
        const f16x8 bfrag = *(const f16x8*)(Yl + YSLOT(col, l4));
        f32x4 z = {0.f, 0.f, 0.f, 0.f};
        f32x4 d = __builtin_amdgcn_mfma_f32_16x16x32_f16(afrag, bfrag, z, 0, 0, 0);
        const float wcol = wk[col];
#pragma unroll
        for (int r = 0; r < 4; ++r) {
            const float ev = EXP2F(fmaf(d[r], TWOK2, wcol - xm[r]));
            e_[4 * t + r] = ev;
            s[r] += ev;
        }
    }
#pragma unroll
    for (int off = 1; off < 16; off <<= 1)
#pragma unroll
        for (int r = 0; r < 4; ++r) s[r] += __shfl_xor(s[r], off);
    if (l15 == 0) {
#pragma unroll
        for (int r = 0; r < 4; ++r) mrg[(wr << 4) + (l4 << 2) + r][wc] = s[r];
    }
    __syncthreads();

    float S = 0.f, uo = 0.f, M0r = 0.f;
    int gr = 0;
    if (tid < 32) {
        S = 0.f;
#pragma unroll
        for (int w = 0; w < 8; ++w) S += mrg[tid][w];
        gr = (b << 10) + (blk << 5) + tid;
        uo = u[gr];
        M0r = (LOGK - uo * INV_EPS) * INV_LN2;
        if (!(S >= 1e-27f && S <= 1e38f)) s_fb = 1;
    }
    __syncthreads();
    const int fb = s_fb;

    if (!fb) {
        if (tid < 32) {
            const float nv = EPSf * (LOGK - (M0r + LOG2F(S)) * LN2f);
            unew[tid] = nv;
            u[gr] = nv;
            const float du = fabsf(nv - uo);
            if (du * K2 > 30.f) s_big = 1;   // tight g-guard (underflow-safe)
            float werr = du;
#pragma unroll
            for (int off = 16; off > 0; off >>= 1) werr += __shfl_xor(werr, off);
            if (tid == 0) atomicAdd(err + it * 16 + b, werr);
        }
    } else {
        // -------- P1 FALLBACK: online max-shifted (it=0, drift) --------
        float m[4] = {-3.4e38f, -3.4e38f, -3.4e38f, -3.4e38f};
        float sf[4] = {0.f, 0.f, 0.f, 0.f};
#pragma unroll 4
        for (int t = 0; t < 8; ++t) {
            const int col = (wc << 7) + (t << 4) + l15;
            const f16x8 bfrag = *(const f16x8*)(Yl + YSLOT(col, l4));
            f32x4 z = {0.f, 0.f, 0.f, 0.f};
            f32x4 d = __builtin_amdgcn_mfma_f32_16x16x32_f16(afrag, bfrag, z, 0, 0, 0);
            const float wcol = wk[col];
#pragma unroll
            for (int r = 0; r < 4; ++r) {
                const float a2  = fmaf(d[r], TWOK2, wcol - xk[r]);
                const float big = fmaxf(m[r], a2);
                const float e   = EXP2F(fminf(m[r], a2) - big);
                sf[r] = (a2 > m[r]) ? fmaf(sf[r], e, 1.0f) : (sf[r] + e);
                m[r] = big;
            }
        }
#pragma unroll
        for (int off = 1; off < 16; off <<= 1)
#pragma unroll
            for (int r = 0; r < 4; ++r)
                msmerge(m[r], sf[r], __shfl_xor(m[r], off), __shfl_xor(sf[r], off));
        if (l15 == 0) {
#pragma unroll
            for (int r = 0; r < 4; ++r) {
                const int rb = (wr << 4) + (l4 << 2) + r;
                mrg[rb][wc]     = m[r];
                mrg[rb][8 + wc] = sf[r];
            }
        }
        __syncthreads();
        if (tid < 32) {
            float M = mrg[tid][0], Sf = mrg[tid][8];
#pragma unroll
            for (int w = 1; w < 8; ++w) msmerge(M, Sf, mrg[tid][w], mrg[tid][8 + w]);
            const float nv = EPSf * (LOGK - (M + LOG2F(Sf)) * LN2f);
            unew[tid] = nv;
            u[gr] = nv;
            float werr = fabsf(nv - uo);
#pragma unroll
            for (int off = 16; off > 0; off >>= 1) werr += __shfl_xor(werr, off);
            if (tid == 0) atomicAdd(err + it * 16 + b, werr);
        }
    }
    __syncthreads();   // unew, s_big visible
    const int big = s_big;
    const bool exact = fb || big || ((it & 7) == 0);

    if (!exact) {
        // -------- P2 CHEAP: cs_j = sum_i e_ij * g_i (no MFMA, no exp2 sweep)
        float g4[4];
#pragma unroll
        for (int r = 0; r < 4; ++r)
            g4[r] = EXP2F((unew[(wr << 4) + (l4 << 2) + r] - u4o[r]) * K2);
        float cs[8];
#pragma unroll
        for (int t = 0; t < 8; ++t)
            cs[t] = fmaf(e_[4*t], g4[0], fmaf(e_[4*t+1], g4[1],
                    fmaf(e_[4*t+2], g4[2], e_[4*t+3] * g4[3])));
#pragma unroll
        for (int off = 16; off <= 32; off <<= 1)
#pragma unroll
            for (int t = 0; t < 8; ++t) cs[t] += __shfl_xor(cs[t], off);
        if (l4 == 0) {
#pragma unroll
            for (int t = 0; t < 8; ++t) {
                const int col = (wc << 7) + (t << 4) + l15;
                colp[(wr << 10) + col] = make_float2(mcl[col], cs[t]);
            }
        }
    } else {
        // -------- P2 EXACT: absolute-domain online (r10-proven) --------
        float am[4];
#pragma unroll
        for (int r = 0; r < 4; ++r)
            am[r] = unew[(wr << 4) + (l4 << 2) + r] * K2 - xk[r];
        float cm[8], cs[8];
#pragma unroll
        for (int t = 0; t < 8; ++t) { cm[t] = -3.4e38f; cs[t] = 0.f; }
#pragma unroll 4
        for (int t = 0; t < 8; ++t) {
            const int col = (wc << 7) + (t << 4) + l15;
            const float mct = mcl[col];
            const float bcol = bk2[col];
            const f16x8 bfrag = *(const f16x8*)(Yl + YSLOT(col, l4));
            f32x4 z = {0.f, 0.f, 0.f, 0.f};
            f32x4 d = __builtin_amdgcn_mfma_f32_16x16x32_f16(afrag, bfrag, z, 0, 0, 0);
#pragma unroll
            for (int r = 0; r < 4; ++r) {
                const float a2  = fmaf(d[r], TWOK2, am[r] - bcol) + mct;
                const float bg  = fmaxf(cm[t], a2);
                const float e   = EXP2F(fminf(cm[t], a2) - bg);
                cs[t] = (a2 > cm[t]) ? fmaf(cs[t], e, 1.0f) : (cs[t] + e);
                cm[t] = bg;
            }
        }
#pragma unroll
        for (int off = 16; off <= 32; off <<= 1)
#pragma unroll
            for (int t = 0; t < 8; ++t) {
                const float mo = __shfl_xor(cm[t], off);
                const float so = __shfl_xor(cs[t], off);
                msmerge(cm[t], cs[t], mo, so);
            }
        __syncthreads();   // all Yl reads done -> colp may overwrite
        if (l4 == 0) {
#pragma unroll
            for (int t = 0; t < 8; ++t) {
                const int col = (wc << 7) + (t << 4) + l15;
                colp[(wr << 10) + col] = make_float2(cm[t], cs[t]);
            }
        }
    }
    __syncthreads();

    // cross-stripe merge + coalesced store of this block's column partial
    {
        float2 q0 = colp[tid], q1 = colp[1024 + tid];
        float M = q0.x, Sv = q0.y;
        msmerge(M, Sv, q1.x, q1.y);
        Sp[((((size_t)b << 5) + blk) << 10) + tid] = make_float2(M, Sv);
    }
}

// ---------------------------------------------------------------------------
// cost = mean_b sum_ij exp((u_i + v_j - C_ij)/eps) * C_ij; v_final combined
// from the 32 Sp partials (same math as P0); C via the SAME fp16+MFMA path.
// ---------------------------------------------------------------------------
__global__ __launch_bounds__(1024, 1) void cost_mfma(
    const _Float16* __restrict__ Xh, const _Float16* __restrict__ Yh,
    const float* __restrict__ xsq, const float* __restrict__ ysq,
    const float* __restrict__ u, const float2* __restrict__ Sp,
    float* __restrict__ out)
{
    __shared__ _Float16 Yl[32768];
    __shared__ float vkl[1024];   // v_final * K2
    __shared__ float red[16];
    const int tid = threadIdx.x;
    const int b   = blockIdx.x & 15, blk = blockIdx.x >> 4;

    {   const float4* src = (const float4*)(Yh + ((size_t)b << 15));
#pragma unroll
        for (int i = 0; i < 4; ++i) {
            const int g = tid + (i << 10);
            const int row = g >> 2, k = g & 3;
            *(float4*)(Yl + YSLOT(row, k)) = src[g];
        }
        const float2* sp = Sp + ((size_t)b << 15) + tid;
        float2 p0 = sp[0];
        float M = p0.x, S = p0.y;
#pragma unroll 8
        for (int k = 1; k < 32; ++k) {
            float2 p = sp[k << 10];
            msmerge(M, S, p.x, p.y);
        }
        S = fmaxf(S, 1e-37f);
        vkl[tid] = EPSf * (LOGK - (M + LOG2F(S)) * LN2f) * K2;
    }
    __syncthreads();

    const int wave = tid >> 6, lane = tid & 63;
    const int wr = wave >> 2, wc = wave & 3;
    const int l15 = lane & 15, l4 = lane >> 4;
    const int rowb = (blk << 6) + (wr << 4);

    const f16x8 afrag = *(const f16x8*)(Xh + ((size_t)b << 15) +
                                        ((size_t)(rowb + l15) << 5) + (l4 << 3));
    const float4 xs4 = *(const float4*)(xsq + (b << 10) + rowb + (l4 << 2));
    const float xs[4] = {xs4.x, xs4.y, xs4.z, xs4.w};
    const float4 uu4 = *(const float4*)(u + (b << 10) + rowb + (l4 << 2));
    const float uk[4] = {uu4.x * K2, uu4.y * K2, uu4.z * K2, uu4.w * K2};

    float vk[16], ys[16];
#pragma unroll
    for (int t = 0; t < 16; ++t) {
        const int cl = (wc << 8) + (t << 4) + l15;
        vk[t] = vkl[cl];
        ys[t] = ysq[(b << 10) + cl];
    }

    float csum = 0.f;
#pragma unroll 4
    for (int t = 0; t < 16; ++t) {
        const int col = (wc << 8) + (t << 4) + l15;
        const f16x8 bfrag = *(const f16x8*)(Yl + YSLOT(col, l4));
        f32x4 z = {0.f, 0.f, 0.f, 0.f};
        f32x4 d = __builtin_amdgcn_mfma_f32_16x16x32_f16(afrag, bfrag, z, 0, 0, 0);
#pragma unroll
        for (int r = 0; r < 4; ++r) {
            const float C   = fmaf(-2.f, d[r], xs[r] + ys[t]);
            const float arg = fmaf(C, -K2, uk[r] + vk[t]);
            csum += EXP2F(arg) * C;
        }
    }
#pragma unroll
    for (int off = 32; off > 0; off >>= 1) csum += __shfl_xor(csum, off);

    if (lane == 0) red[wave] = csum;
    __syncthreads();
    if (tid == 0) {
        float tot = 0.f;
#pragma unroll
        for (int w = 0; w < 16; ++w) tot += red[w];
        atomicAdd(out, tot * (1.0f / 16.0f));
    }
}

extern "C" void kernel_launch(void* const* d_in, const int* in_sizes, int n_in,
                              void* d_out, int out_size, void* d_ws, size_t ws_size,
                              hipStream_t stream) {
    const float* x = (const float*)d_in[0];  // output: [16,1024,32] fp32
    const float* y = (const float*)d_in[1];  // labels: [16,1024,32] fp32

    char* wsb = (char*)d_ws;
    _Float16* Xh = (_Float16*)wsb;                     // 1 MB  [16][1024][32]
    _Float16* Yh = (_Float16*)(wsb + (1u << 20));      // 1 MB
    float2* Sp   = (float2*)(wsb + (2u << 20));        // 4 MB  [512][1024]
    float* xsq   = (float*)(wsb + (6u << 20));         // 16384 f
    float* ysq   = xsq + 16384;                        // 16384 f
    float* u     = ysq + 16384;                        // 16384 f
    float* err   = u + 16384;                          // [100][16]
    float* out   = (float*)d_out;

    // u and err contiguous — zero them (+ out) every call
    (void)hipMemsetAsync(u, 0, (size_t)(16384 + 1600) * 4, stream);
    (void)hipMemsetAsync(out, 0, sizeof(float), stream);

    prep<<<dim3(128), dim3(256), 0, stream>>>(x, y, Xh, Yh, xsq, ysq);

    // one dispatch per iteration (u-update + v-partials fused)
    for (int it = 0; it < MAX_ITER; ++it)
        sink_iter<<<dim3(512), dim3(1024), 0, stream>>>(
            Xh, Yh, xsq, ysq, u, Sp, err, it);

    cost_mfma<<<dim3(256), dim3(1024), 0, stream>>>(Xh, Yh, xsq, ysq, u, Sp, out);
}

// Round 14
// 1358.575 us; speedup vs baseline: 1.7386x; 1.7386x over previous
//
#include <hip/hip_runtime.h>

// Problem constants (B=16, N=M=1024, D=32)
constexpr int   NN       = 1024;
constexpr float EPSf     = 1e-3f;
constexpr int   MAX_ITER = 100;

// exp2-domain scale: arg = (v - C) * (1/eps) * log2(e)
#define K2      1442.6950408889634f
#define TWOK2   2885.3900817779268f
#define LN2f    0.6931471805599453f
#define INV_LN2 1.4426950408889634f
#define INV_EPS 1000.0f
#define LOGK    (-6.9314616f)   // log(1/1024 + 1e-8)

#define EXP2F(x) __builtin_amdgcn_exp2f(x)   // 2^x
#define LOG2F(x) __builtin_amdgcn_logf(x)    // log2(x)

typedef _Float16 f16x8 __attribute__((ext_vector_type(8)));
typedef float    f32x4 __attribute__((ext_vector_type(4)));

// (m,s) streaming-LSE merge: (ma,sa) <- (ma,sa) (+) (mb,sb)
__device__ __forceinline__ void msmerge(float& ma, float& sa, float mb, float sb)
{
    const float m2 = fmaxf(ma, mb);
    sa = fmaf(sa, EXP2F(ma - m2), sb * EXP2F(mb - m2));
    ma = m2;
}

// ---------------------------------------------------------------------------
// prep: X,Y fp32 -> fp16 copies + fp32 row sum-of-squares. One thread per row.
// C is NEVER materialized: every consumer computes C = xsq_i + ysq_j - 2<x,y>
// with the same fp16 operands + MFMA, so C is consistent across all kernels.
// ---------------------------------------------------------------------------
__global__ __launch_bounds__(256) void prep(
    const float* __restrict__ X, const float* __restrict__ Y,
    _Float16* __restrict__ Xh, _Float16* __restrict__ Yh,
    float* __restrict__ xsq, float* __restrict__ ysq)
{
    const int gid = blockIdx.x * 256 + threadIdx.x;   // 0..32767
    const float* src; _Float16* dst; float* sq; int row;
    if (gid < 16384) { src = X; dst = Xh; sq = xsq; row = gid; }
    else             { src = Y; dst = Yh; sq = ysq; row = gid - 16384; }

    const float4* s4 = (const float4*)(src + (size_t)row * 32);
    float acc = 0.f;
#pragma unroll
    for (int i = 0; i < 4; ++i) {
        float4 a = s4[2 * i], b = s4[2 * i + 1];
        acc += a.x*a.x + a.y*a.y + a.z*a.z + a.w*a.w;
        acc += b.x*b.x + b.y*b.y + b.z*b.z + b.w*b.w;
        f16x8 h = {(_Float16)a.x, (_Float16)a.y, (_Float16)a.z, (_Float16)a.w,
                   (_Float16)b.x, (_Float16)b.y, (_Float16)b.z, (_Float16)b.w};
        *(f16x8*)(dst + (size_t)row * 32 + i * 8) = h;
    }
    sq[row] = acc;
}

// XOR-swizzled LDS slot for row/col c, 16B-chunk k: kills the 4x bank
// serialization of the linear layout (quarter-wave banks were {0,16}+4k).
// Enumeration: read quarter (fixed l4, c=base..base+15) hits all 32 banks
// exactly twice (ideal for b128); staging writes likewise 8/bank.
#define YSLOT(c, k) (((c) << 5) + (((k) ^ (((c) >> 1) & 3)) << 3))   // f16 units

// ---------------------------------------------------------------------------
// One Sinkhorn half-step via MFMA, C on the fly (C = asq_i + bsq_j - 2<a,b>).
// Grid 256 x 1024: block (b = blk&15) owns 64 rows x 1024 cols of batch b
// (b&7 pins a batch's 16 blocks to one XCD -> Bh[b] L2-hot).
// FAST PATH (baseline-proven): shift args by M0 derived from the PREVIOUS
// iterate (no max pass, plain sums); block-uniform FALLBACK to online
// max-shifted LSE when any row's sum leaves (1e-27, 1e38) — fires at it=0.
// Frag layouts (verified): D col=lane&15,row=(lane>>4)*4+reg; A row=lane&15,
// k=(lane>>4)*8+j; B col=lane&15, k=(lane>>4)*8+j.
// ---------------------------------------------------------------------------
__global__ __launch_bounds__(1024, 1) void lse_mfma_pass(
    const _Float16* __restrict__ Ah,   // row-side fp16 [16][1024][32]
    const _Float16* __restrict__ Bh,   // col-side fp16
    const float* __restrict__ asq,     // |a_i|^2
    const float* __restrict__ bsq,     // |b_j|^2
    const float* __restrict__ vin,     // v (u-pass) / u (v-pass)
    float* __restrict__ vout,          // u (u-pass) / v (v-pass)
    float* __restrict__ err,           // err[16][128]
    int* __restrict__ dflag, int it, int do_err)
{
    __shared__ _Float16 Yl[32768];     // 64 KB B-tile, swizzled rows
    __shared__ float    wk[1024];      // (vin - bsq) * K2 per column
    __shared__ float    mrg[64][8];    // per-row per-wc partials
    __shared__ int      s_fb;

    const int tid = threadIdx.x;
    const int b   = blockIdx.x & 15, blk = blockIdx.x >> 4;

    // freeze chain (v-pass only; err[.][it] complete from this it's u-pass)
    if (!do_err && blockIdx.x == 0 && tid < 16) {
        float e = err[(tid << 7) + it];
        e += __shfl_xor(e, 1); e += __shfl_xor(e, 2);
        e += __shfl_xor(e, 4); e += __shfl_xor(e, 8);
        if (tid == 0) dflag[it + 1] = dflag[it] | (e < 1.6f ? 1 : 0);
    }
    if (dflag[it]) return;   // frozen: u,v keep their converged values
    if (tid == 0) s_fb = 0;

    {   // stage Bh[b] (64 KB) swizzled + wk (4 KB)
        const float4* src = (const float4*)(Bh + ((size_t)b << 15));
#pragma unroll
        for (int i = 0; i < 4; ++i) {
            const int g = tid + (i << 10);
            const int row = g >> 2, k = g & 3;
            *(float4*)(Yl + YSLOT(row, k)) = src[g];
        }
        const int c = (b << 10) + tid;
        wk[tid] = (vin[c] - bsq[c]) * K2;
    }
    __syncthreads();

    const int wave = tid >> 6, lane = tid & 63;
    const int wr = wave >> 2, wc = wave & 3;
    const int l15 = lane & 15, l4 = lane >> 4;
    const int rowb = (blk << 6) + (wr << 4);            // wave's 16-row stripe

    // A fragment: rows rowb+l15, k = l4*8..+7 (wave covers 1 KB contiguously)
    const f16x8 afrag = *(const f16x8*)(Ah + ((size_t)b << 15) +
                                        ((size_t)(rowb + l15) << 5) + (l4 << 3));
    // per-D-row terms: rows rowb + l4*4 + r
    const float4 xs4 = *(const float4*)(asq + (b << 10) + rowb + (l4 << 2));
    const float4 uo4 = *(const float4*)(vout + (b << 10) + rowb + (l4 << 2));
    const float xk[4] = {xs4.x * K2, xs4.y * K2, xs4.z * K2, xs4.w * K2};
    // xm = asq*K2 + M0,  M0 = (LOGK - uo/eps)/ln2  (prev-iterate shift)
    float xm[4];
    {
        const float u4[4] = {uo4.x, uo4.y, uo4.z, uo4.w};
#pragma unroll
        for (int r = 0; r < 4; ++r)
            xm[r] = xk[r] + (LOGK - u4[r] * INV_EPS) * INV_LN2;
    }

    // per-col terms for this lane's 16 tile-columns
    float wreg[16];
#pragma unroll
    for (int t = 0; t < 16; ++t) wreg[t] = wk[(wc << 8) + (t << 4) + l15];

    // ---------------- FAST PATH: plain sums shifted by M0 ----------------
    float s[4] = {0.f, 0.f, 0.f, 0.f};
#pragma unroll 4
    for (int t = 0; t < 16; ++t) {
        const int col = (wc << 8) + (t << 4) + l15;
        const f16x8 bfrag = *(const f16x8*)(Yl + YSLOT(col, l4));
        f32x4 z = {0.f, 0.f, 0.f, 0.f};
        f32x4 d = __builtin_amdgcn_mfma_f32_16x16x32_f16(afrag, bfrag, z, 0, 0, 0);
#pragma unroll
        for (int r = 0; r < 4; ++r)
            s[r] += EXP2F(fmaf(d[r], TWOK2, wreg[t] - xm[r]));
    }
#pragma unroll
    for (int off = 1; off < 16; off <<= 1)
#pragma unroll
        for (int r = 0; r < 4; ++r) s[r] += __shfl_xor(s[r], off);
    if (l15 == 0) {
#pragma unroll
        for (int r = 0; r < 4; ++r) mrg[(wr << 4) + (l4 << 2) + r][wc] = s[r];
    }
    __syncthreads();

    // range check (wave 0) -> block-uniform fallback decision
    float S = 0.f, uo = 0.f, M0r = 0.f;
    int gr = 0;
    if (tid < 64) {
        S = mrg[tid][0] + mrg[tid][1] + mrg[tid][2] + mrg[tid][3];
        gr = (b << 10) + (blk << 6) + tid;
        uo = vout[gr];
        M0r = (LOGK - uo * INV_EPS) * INV_LN2;
        if (!(S >= 1e-27f && S <= 1e38f)) s_fb = 1;
    }
    __syncthreads();

    if (!s_fb) {
        if (tid < 64) {
            const float lse2 = M0r + LOG2F(S);
            const float nv = EPSf * (LOGK - lse2 * LN2f);
            float werr = do_err ? fabsf(nv - uo) : 0.f;
            vout[gr] = nv;
#pragma unroll
            for (int off = 32; off > 0; off >>= 1) werr += __shfl_xor(werr, off);
            if (do_err && tid == 0) atomicAdd(err + (b << 7) + it, werr);
        }
        return;
    }

    // ------------- FALLBACK: online max-shifted LSE (it=0, drift) -------------
    float m[4] = {-3.4e38f, -3.4e38f, -3.4e38f, -3.4e38f};
    float sf[4] = {0.f, 0.f, 0.f, 0.f};
#pragma unroll 4
    for (int t = 0; t < 16; ++t) {
        const int col = (wc << 8) + (t << 4) + l15;
        const f16x8 bfrag = *(const f16x8*)(Yl + YSLOT(col, l4));
        f32x4 z = {0.f, 0.f, 0.f, 0.f};
        f32x4 d = __builtin_amdgcn_mfma_f32_16x16x32_f16(afrag, bfrag, z, 0, 0, 0);
#pragma unroll
        for (int r = 0; r < 4; ++r) {
            const float arg = fmaf(d[r], TWOK2, wreg[t] - xk[r]);
            const float big = fmaxf(m[r], arg);
            const float e   = EXP2F(fminf(m[r], arg) - big);
            sf[r] = (arg > m[r]) ? fmaf(sf[r], e, 1.0f) : (sf[r] + e);
            m[r] = big;
        }
    }
#pragma unroll
    for (int off = 1; off < 16; off <<= 1)
#pragma unroll
        for (int r = 0; r < 4; ++r)
            msmerge(m[r], sf[r], __shfl_xor(m[r], off), __shfl_xor(sf[r], off));
    if (l15 == 0) {
#pragma unroll
        for (int r = 0; r < 4; ++r) {
            const int rb = (wr << 4) + (l4 << 2) + r;
            mrg[rb][wc]     = m[r];
            mrg[rb][4 + wc] = sf[r];
        }
    }
    __syncthreads();

    if (tid < 64) {
        float M = mrg[tid][0], Sf = mrg[tid][4];
        msmerge(M, Sf, mrg[tid][1], mrg[tid][5]);
        msmerge(M, Sf, mrg[tid][2], mrg[tid][6]);
        msmerge(M, Sf, mrg[tid][3], mrg[tid][7]);
        const float lse2 = M + LOG2F(Sf);
        const float nv = EPSf * (LOGK - lse2 * LN2f);
        float werr = do_err ? fabsf(nv - uo) : 0.f;
        vout[gr] = nv;
#pragma unroll
        for (int off = 32; off > 0; off >>= 1) werr += __shfl_xor(werr, off);
        if (do_err && tid == 0) atomicAdd(err + (b << 7) + it, werr);
    }
}

// ---------------------------------------------------------------------------
// cost = mean_b sum_ij exp((u_i + v_j - C_ij)/eps) * C_ij, C via the SAME
// fp16+MFMA path (consistency with the (u,v) fixed point is mandatory).
// Same geometry + swizzle as lse_mfma_pass.
// ---------------------------------------------------------------------------
__global__ __launch_bounds__(1024, 1) void cost_mfma(
    const _Float16* __restrict__ Xh, const _Float16* __restrict__ Yh,
    const float* __restrict__ xsq, const float* __restrict__ ysq,
    const float* __restrict__ u, const float* __restrict__ v,
    float* __restrict__ out)
{
    __shared__ _Float16 Yl[32768];
    __shared__ float red[16];
    const int tid = threadIdx.x;
    const int b   = blockIdx.x & 15, blk = blockIdx.x >> 4;

    {   const float4* src = (const float4*)(Yh + ((size_t)b << 15));
#pragma unroll
        for (int i = 0; i < 4; ++i) {
            const int g = tid + (i << 10);
            const int row = g >> 2, k = g & 3;
            *(float4*)(Yl + YSLOT(row, k)) = src[g];
        }
    }
    __syncthreads();

    const int wave = tid >> 6, lane = tid & 63;
    const int wr = wave >> 2, wc = wave & 3;
    const int l15 = lane & 15, l4 = lane >> 4;
    const int rowb = (blk << 6) + (wr << 4);

    const f16x8 afrag = *(const f16x8*)(Xh + ((size_t)b << 15) +
                                        ((size_t)(rowb + l15) << 5) + (l4 << 3));
    const float4 xs4 = *(const float4*)(xsq + (b << 10) + rowb + (l4 << 2));
    const float xs[4] = {xs4.x, xs4.y, xs4.z, xs4.w};
    const float4 uu4 = *(const float4*)(u + (b << 10) + rowb + (l4 << 2));
    const float uk[4] = {uu4.x * K2, uu4.y * K2, uu4.z * K2, uu4.w * K2};

    float vk[16], ys[16];
#pragma unroll
    for (int t = 0; t < 16; ++t) {
        const int c = (b << 10) + (wc << 8) + (t << 4) + l15;
        vk[t] = v[c] * K2;
        ys[t] = ysq[c];
    }

    float csum = 0.f;
#pragma unroll 4
    for (int t = 0; t < 16; ++t) {
        const int col = (wc << 8) + (t << 4) + l15;
        const f16x8 bfrag = *(const f16x8*)(Yl + YSLOT(col, l4));
        f32x4 z = {0.f, 0.f, 0.f, 0.f};
        f32x4 d = __builtin_amdgcn_mfma_f32_16x16x32_f16(afrag, bfrag, z, 0, 0, 0);
#pragma unroll
        for (int r = 0; r < 4; ++r) {
            const float C   = fmaf(-2.f, d[r], xs[r] + ys[t]);
            const float arg = fmaf(C, -K2, uk[r] + vk[t]);
            csum += EXP2F(arg) * C;
        }
    }
#pragma unroll
    for (int off = 32; off > 0; off >>= 1) csum += __shfl_xor(csum, off);

    if (lane == 0) red[wave] = csum;
    __syncthreads();
    if (tid == 0) {
        float tot = 0.f;
#pragma unroll
        for (int w = 0; w < 16; ++w) tot += red[w];
        atomicAdd(out, tot * (1.0f / 16.0f));
    }
}

extern "C" void kernel_launch(void* const* d_in, const int* in_sizes, int n_in,
                              void* d_out, int out_size, void* d_ws, size_t ws_size,
                              hipStream_t stream) {
    const float* x = (const float*)d_in[0];  // output: [16,1024,32] fp32
    const float* y = (const float*)d_in[1];  // labels: [16,1024,32] fp32

    char* wsb = (char*)d_ws;
    _Float16* Xh = (_Float16*)wsb;                     // 1 MB  [16][1024][32]
    _Float16* Yh = (_Float16*)(wsb + (1u << 20));      // 1 MB
    float* xsq   = (float*)(wsb + (2u << 20));         // 16384 f
    float* ysq   = xsq + 16384;                        // 16384 f
    float* u     = ysq + 16384;                        // 16384 f
    float* v     = u + 16384;                          // 16384 f
    float* err   = v + 16384;                          // [16][128]
    int*   dflag = (int*)(err + 2048);                 // 128
    float* out   = (float*)d_out;

    // u, v, err, dflag contiguous — zero them (+ out) every call
    (void)hipMemsetAsync(u, 0, (size_t)(2 * 16384 + 2048 + 128) * 4, stream);
    (void)hipMemsetAsync(out, 0, sizeof(float), stream);

    prep<<<dim3(128), dim3(256), 0, stream>>>(x, y, Xh, Yh, xsq, ysq);

    for (int it = 0; it < MAX_ITER; ++it) {
        // u-pass: rows = x, cols = y
        lse_mfma_pass<<<dim3(256), dim3(1024), 0, stream>>>(
            Xh, Yh, xsq, ysq, v, u, err, dflag, it, 1);
        // v-pass: rows = y, cols = x
        lse_mfma_pass<<<dim3(256), dim3(1024), 0, stream>>>(
            Yh, Xh, ysq, xsq, u, v, err, dflag, it, 0);
    }

    cost_mfma<<<dim3(256), dim3(1024), 0, stream>>>(Xh, Yh, xsq, ysq, u, v, out);
}